// Round 1
// baseline (90.356 us; speedup 1.0000x reference)
//
#include <hip/hip_runtime.h>
#include <hip/hip_bf16.h>

// StatDynamicConv2d: routing MLP -> expert-mixed 3x3 conv (per-sample weights)
// B=32, Cin=Cout=128, H=W=64, E=4, K=3, pad=1, stride=1.
//
// ws layout (requires ~45.2 MB):
//   [0,512)                routing[32][4] f32
//   [512, 512+16384)       dynb[32][128] f32
//   [32768, +9437184)      dynw[32][9][4][128][32] bf16   (tap-major, 32ci blocks)
//   [9469952, +35684352)   xbfT[32][2][66][66][64] bf16   (zero-padded halo, ci-inner)

typedef short bf16x8 __attribute__((ext_vector_type(8)));
typedef float f32x4  __attribute__((ext_vector_type(4)));

static __device__ __forceinline__ unsigned short f2bf(float f) {
    unsigned u = __float_as_uint(f);
    u = u + 0x7FFFu + ((u >> 16) & 1u);   // round-to-nearest-even
    return (unsigned short)(u >> 16);
}

// ---------------- kernel A: router MLP ----------------
__global__ void router_kernel(const float* __restrict__ stats, const float* __restrict__ W1,
                              const float* __restrict__ b1, const float* __restrict__ W2,
                              const float* __restrict__ b2, float* __restrict__ routing)
{
    int t = threadIdx.x;
    if (t >= 32) return;
    float s[6];
#pragma unroll
    for (int i = 0; i < 6; ++i) s[i] = stats[t*6 + i];
    float h[16];
#pragma unroll
    for (int j = 0; j < 16; ++j) {
        float a = b1[j];
#pragma unroll
        for (int i = 0; i < 6; ++i) a += W1[j*6+i]*s[i];
        h[j] = a > 0.f ? a : 0.f;
    }
    float lg[4];
#pragma unroll
    for (int e = 0; e < 4; ++e) {
        float a = b2[e];
#pragma unroll
        for (int j = 0; j < 16; ++j) a += W2[e*16+j]*h[j];
        lg[e] = a;
    }
    float m = fmaxf(fmaxf(lg[0],lg[1]), fmaxf(lg[2],lg[3]));
    float ex[4], sum = 0.f;
#pragma unroll
    for (int e = 0; e < 4; ++e) { ex[e] = expf(lg[e]-m); sum += ex[e]; }
    float inv = 1.f / sum;
#pragma unroll
    for (int e = 0; e < 4; ++e) routing[t*4+e] = ex[e]*inv;
}

// ---------------- kernel B: dynamic weights (bf16) + dyn bias ----------------
// grid (128 co, 4 bgroups), 256 threads
__global__ void dynw_kernel(const float* __restrict__ wexp, const float* __restrict__ bexp,
                            const float* __restrict__ routing, unsigned short* __restrict__ dynw,
                            float* __restrict__ dynb)
{
    __shared__ float ls[4*1152];
    __shared__ float lr[32*4];
    const int tid = threadIdx.x;
    const int co  = blockIdx.x;
    const int bg  = blockIdx.y;

    for (int i = tid; i < 4*1152; i += 256) {
        int e = i / 1152, j = i - e*1152;
        ls[i] = wexp[((unsigned long long)(e*128 + co))*1152 + j];
    }
    if (tid < 128) lr[tid] = routing[tid];
    __syncthreads();

    if (bg == 0 && tid < 32) {
        float sb = 0.f;
#pragma unroll
        for (int e = 0; e < 4; ++e) sb += lr[tid*4+e] * bexp[e*128 + co];
        dynb[tid*128 + co] = sb;
    }

    const int ci  = tid & 127;
    const int tp0 = tid >> 7;
    for (int bb = bg*8; bb < bg*8 + 8; ++bb) {
        float r0 = lr[bb*4+0], r1 = lr[bb*4+1], r2 = lr[bb*4+2], r3 = lr[bb*4+3];
#pragma unroll
        for (int p = 0; p < 5; ++p) {
            int tap = 2*p + tp0;
            if (tap < 9) {
                int j = ci*9 + tap;
                float v = r0*ls[j] + r1*ls[1152+j] + r2*ls[2*1152+j] + r3*ls[3*1152+j];
                dynw[((((unsigned long long)bb*9 + tap)*4 + (ci>>5))*128 + co)*32 + (ci&31)] = f2bf(v);
            }
        }
    }
}

// ---------------- kernel C: x fp32 -> bf16, transposed + zero halo ----------------
// xbfT[b][h2][rr(66)][lcol(66)][64ci]  ; grid 32*66 blocks, 256 threads
__global__ void xcvt_kernel(const float* __restrict__ x, unsigned int* __restrict__ xbfT)
{
    __shared__ unsigned int ls32[64*66];
    const int tid = threadIdx.x;
    const int b  = blockIdx.x / 66;
    const int rr = blockIdx.x - b*66;
    const int gr = rr - 1;

    if (gr < 0 || gr > 63) {
#pragma unroll
        for (int h = 0; h < 2; ++h) {
            unsigned int* dst = xbfT + ((unsigned long long)(b*2 + h)*66 + rr)*(66*32);
            for (int d = tid; d < 66*32; d += 256) dst[d] = 0u;
        }
        return;
    }
    const int lane = tid & 63;
    const int w    = tid >> 6;
#pragma unroll
    for (int k = 0; k < 16; ++k) {
        int cp = w + 4*k;   // ci pair 0..63
        const float* p0 = x + (((unsigned long long)b*128 + 2*cp)*64 + gr)*64 + lane;
        unsigned lo = f2bf(p0[0]);
        unsigned hi = f2bf(p0[64*64]);
        ls32[cp*66 + lane] = lo | (hi << 16);
    }
    __syncthreads();
#pragma unroll
    for (int h = 0; h < 2; ++h) {
        unsigned int* dst = xbfT + ((unsigned long long)(b*2 + h)*66 + rr)*(66*32);
        for (int d = tid; d < 66*32; d += 256) {
            int lcol = d >> 5;
            int cd   = d & 31;
            unsigned v = (lcol == 0 || lcol == 65) ? 0u : ls32[(h*32 + cd)*66 + (lcol - 1)];
            dst[d] = v;
        }
    }
}

// ---------------- kernel D: implicit-GEMM conv, bf16 MFMA ----------------
// grid 512 (32 b x 16 row-tiles), 256 threads (4 waves), each wave = 1 output row
__global__ __launch_bounds__(256, 2) void conv_kernel(
    const unsigned short* __restrict__ xbfT,
    const unsigned short* __restrict__ dynw,
    const float* __restrict__ dynb,
    float* __restrict__ out)
{
    // xs: [6 rows][66 cols][64 ci], 16B chunks XOR-swizzled by (col&7)
    __shared__ __align__(16) unsigned short xs[6*66*64];
    // wsm: [128 co][32 ci], 16B chunks XOR-swizzled by (co&3)
    __shared__ __align__(16) unsigned short wsm[128*32];

    const int tid  = threadIdx.x;
    const int wave = tid >> 6;
    const int lane = tid & 63;
    const int l15  = lane & 15;
    const int g    = lane >> 4;

    const int bidx = blockIdx.x;
    const int b    = bidx >> 4;
    const int tile = bidx & 15;
    const int r0   = tile * 4;

    f32x4 acc[8][4];
#pragma unroll
    for (int mi = 0; mi < 8; ++mi)
#pragma unroll
        for (int ni = 0; ni < 4; ++ni) acc[mi][ni] = (f32x4){0.f, 0.f, 0.f, 0.f};

    const unsigned long long xbase = (unsigned long long)b * (2ull*66*66*64);
    const unsigned long long wbase = (unsigned long long)b * (9ull*4*128*32);

    for (int cic = 0; cic < 2; ++cic) {
        __syncthreads();  // protect xs (and wsm) against previous-round reads
        {   // stage xs: 6 rows x 66 cols x 64 ci  (fully contiguous global reads)
            const unsigned short* src = xbfT + xbase + (unsigned long long)cic*(66u*66*64)
                                        + (unsigned long long)r0*(66*64);
            for (int c = tid; c < 6*66*8; c += 256) {
                int cig  = c & 7;
                int lcol = (c >> 3) % 66;
                int i    = c / (66*8);
                const int4 v = *(const int4*)(src + (i*66 + lcol)*64 + cig*8);
                int dstb = (i*66 + lcol)*128 + ((cig ^ (lcol & 7)) << 4);
                *(int4*)((char*)xs + dstb) = v;
            }
        }
        for (int tap = 0; tap < 9; ++tap) {
            const int ky = tap / 3, kx = tap - ky*3;
            for (int h = 0; h < 2; ++h) {
                __syncthreads();  // wsm reads of previous round done (also covers xs stage->read)
                {   // stage wsm: dynw[b][tap][cic*2+h][:][:] : 8192 contiguous elems
                    const unsigned short* wsrc = dynw + wbase
                        + (((unsigned long long)tap*4 + (unsigned)(cic*2 + h))*128)*32;
                    for (int c = tid; c < 512; c += 256) {
                        const int4 v = *(const int4*)(wsrc + c*8);
                        int co2 = c >> 2, cig = c & 3;
                        int dstb = co2*64 + ((cig ^ (co2 & 3)) << 4);
                        *(int4*)((char*)wsm + dstb) = v;
                    }
                }
                __syncthreads();
                // one K=32 step
                bf16x8 bfrag[4];
#pragma unroll
                for (int ni = 0; ni < 4; ++ni) {
                    int lcol = 16*ni + l15 + kx;
                    int lrow = wave + ky;
                    int byteoff = (lrow*66 + lcol)*128 + (((h*4 + g) ^ (lcol & 7)) << 4);
                    bfrag[ni] = *(const bf16x8*)((const char*)xs + byteoff);
                }
#pragma unroll
                for (int mi = 0; mi < 8; ++mi) {
                    int co = 16*mi + l15;
                    int byteoff = co*64 + ((g ^ (co & 3)) << 4);
                    bf16x8 afrag = *(const bf16x8*)((const char*)wsm + byteoff);
#pragma unroll
                    for (int ni = 0; ni < 4; ++ni)
                        acc[mi][ni] = __builtin_amdgcn_mfma_f32_16x16x32_bf16(
                                          afrag, bfrag[ni], acc[mi][ni], 0, 0, 0);
                }
            }
        }
    }

    // epilogue: D row = co = 16*mi + g*4 + r ; col = 16*ni + l15 ; y = r0 + wave
    const int y = r0 + wave;
#pragma unroll
    for (int mi = 0; mi < 8; ++mi) {
#pragma unroll
        for (int r = 0; r < 4; ++r) {
            int co = 16*mi + g*4 + r;
            float bias = dynb[b*128 + co];
            float* op = out + (((unsigned long long)(b*128 + co))*64 + y)*64;
#pragma unroll
            for (int ni = 0; ni < 4; ++ni)
                op[16*ni + l15] = acc[mi][ni][r] + bias;
        }
    }
}

extern "C" void kernel_launch(void* const* d_in, const int* in_sizes, int n_in,
                              void* d_out, int out_size, void* d_ws, size_t ws_size,
                              hipStream_t stream)
{
    const float* x     = (const float*)d_in[0];
    const float* stats = (const float*)d_in[1];
    const float* W1    = (const float*)d_in[2];
    const float* b1    = (const float*)d_in[3];
    const float* W2    = (const float*)d_in[4];
    const float* b2    = (const float*)d_in[5];
    const float* wexp  = (const float*)d_in[6];
    const float* bexp  = (const float*)d_in[7];
    float* out = (float*)d_out;

    char* ws = (char*)d_ws;
    float* routing        = (float*)ws;                         // 512 B
    float* dynb           = (float*)(ws + 512);                 // 16 KB
    unsigned short* dynw  = (unsigned short*)(ws + 32768);      // 9,437,184 B
    unsigned short* xbfT  = (unsigned short*)(ws + 32768 + 9437184); // 35,684,352 B

    router_kernel<<<1, 64, 0, stream>>>(stats, W1, b1, W2, b2, routing);
    dynw_kernel<<<dim3(128, 4), 256, 0, stream>>>(wexp, bexp, routing, dynw, dynb);
    xcvt_kernel<<<32*66, 256, 0, stream>>>(x, (unsigned int*)xbfT);
    conv_kernel<<<512, 256, 0, stream>>>(xbfT, dynw, dynb, out);
}

// Round 2
// 77.013 us; speedup vs baseline: 1.1733x; 1.1733x over previous
//
#include <hip/hip_runtime.h>
#include <hip/hip_bf16.h>

// StatDynamicConv2d: routing MLP -> expert-mixed 3x3 conv (per-sample weights)
// B=32, Cin=Cout=128, H=W=64, E=4, K=3, pad=1, stride=1.
//
// ws layout (~45.2 MB):
//   [0,512)                routing[32][4] f32
//   [512, 512+16384)       dynb[32][128] f32
//   [32768, +9437184)      dynw[32][4cic][9tap][128co][32ci] bf16, 16B chunks
//                          swizzled: chunk cg stored at (cg + (co>>1))&3
//   [9469952, +35684352)   xbfT[32][4cic][66][66][32ci] bf16, halo baked,
//                          swizzled: chunk cg stored at (cg + (lcol>>1))&3

typedef short bf16x8 __attribute__((ext_vector_type(8)));
typedef float f32x4  __attribute__((ext_vector_type(4)));

static __device__ __forceinline__ unsigned short f2bf(float f) {
    unsigned u = __float_as_uint(f);
    u = u + 0x7FFFu + ((u >> 16) & 1u);   // round-to-nearest-even
    return (unsigned short)(u >> 16);
}

static __device__ __forceinline__ void gl2lds16(const unsigned short* g, unsigned short* l) {
    __builtin_amdgcn_global_load_lds(
        (const __attribute__((address_space(1))) unsigned int*)g,
        (__attribute__((address_space(3))) unsigned int*)l,
        16, 0, 0);
}

// ---------------- kernel A: router MLP ----------------
__global__ void router_kernel(const float* __restrict__ stats, const float* __restrict__ W1,
                              const float* __restrict__ b1, const float* __restrict__ W2,
                              const float* __restrict__ b2, float* __restrict__ routing)
{
    int t = threadIdx.x;
    if (t >= 32) return;
    float s[6];
#pragma unroll
    for (int i = 0; i < 6; ++i) s[i] = stats[t*6 + i];
    float h[16];
#pragma unroll
    for (int j = 0; j < 16; ++j) {
        float a = b1[j];
#pragma unroll
        for (int i = 0; i < 6; ++i) a += W1[j*6+i]*s[i];
        h[j] = a > 0.f ? a : 0.f;
    }
    float lg[4];
#pragma unroll
    for (int e = 0; e < 4; ++e) {
        float a = b2[e];
#pragma unroll
        for (int j = 0; j < 16; ++j) a += W2[e*16+j]*h[j];
        lg[e] = a;
    }
    float m = fmaxf(fmaxf(lg[0],lg[1]), fmaxf(lg[2],lg[3]));
    float ex[4], sum = 0.f;
#pragma unroll
    for (int e = 0; e < 4; ++e) { ex[e] = expf(lg[e]-m); sum += ex[e]; }
    float inv = 1.f / sum;
#pragma unroll
    for (int e = 0; e < 4; ++e) routing[t*4+e] = ex[e]*inv;
}

// ---------------- kernel B: dynamic weights (bf16, pre-swizzled) + dyn bias ----------------
__global__ void dynw_kernel(const float* __restrict__ wexp, const float* __restrict__ bexp,
                            const float* __restrict__ routing, unsigned short* __restrict__ dynw,
                            float* __restrict__ dynb)
{
    __shared__ float ls[4*1152];
    __shared__ float lr[32*4];
    const int tid = threadIdx.x;
    const int co  = blockIdx.x;
    const int bg  = blockIdx.y;

    for (int i = tid; i < 4*1152; i += 256) {
        int e = i / 1152, j = i - e*1152;
        ls[i] = wexp[((unsigned long long)(e*128 + co))*1152 + j];
    }
    if (tid < 128) lr[tid] = routing[tid];
    __syncthreads();

    if (bg == 0 && tid < 32) {
        float sb = 0.f;
#pragma unroll
        for (int e = 0; e < 4; ++e) sb += lr[tid*4+e] * bexp[e*128 + co];
        dynb[tid*128 + co] = sb;
    }

    const int ci  = tid & 127;
    const int tp0 = tid >> 7;
    const int cic = ci >> 5;
    const int cg  = (ci >> 3) & 3;
    const int e8  = ci & 7;
    const int p   = (cg + (co >> 1)) & 3;           // bank-conflict-free swizzle
    for (int bb = bg*8; bb < bg*8 + 8; ++bb) {
        float r0 = lr[bb*4+0], r1 = lr[bb*4+1], r2 = lr[bb*4+2], r3 = lr[bb*4+3];
#pragma unroll
        for (int pp = 0; pp < 5; ++pp) {
            int tap = 2*pp + tp0;
            if (tap < 9) {
                int j = ci*9 + tap;
                float v = r0*ls[j] + r1*ls[1152+j] + r2*ls[2*1152+j] + r3*ls[3*1152+j];
                dynw[((((unsigned long long)bb*4 + cic)*9 + tap)*128 + co)*32 + p*8 + e8] = f2bf(v);
            }
        }
    }
}

// ---------------- kernel C: x fp32 -> bf16, transposed + halo + swizzle baked ----------------
// grid 32*66 blocks, 256 threads
__global__ void xcvt_kernel(const float* __restrict__ x, unsigned short* __restrict__ xbfT)
{
    __shared__ unsigned int ls32[64*66];
    const int tid = threadIdx.x;
    const int b  = blockIdx.x / 66;
    const int rr = blockIdx.x - b*66;
    const int gr = rr - 1;

    if (gr < 0 || gr > 63) {
        for (int cic = 0; cic < 4; ++cic) {
            int4* dst = (int4*)(xbfT + ((unsigned long long)((b*4 + cic)*66 + rr))*(66*32));
            for (int d = tid; d < 264; d += 256) dst[d] = make_int4(0,0,0,0);
        }
        return;
    }
    const int lane = tid & 63;
    const int w    = tid >> 6;
#pragma unroll
    for (int k = 0; k < 16; ++k) {
        int cp = w + 4*k;   // ci pair 0..63
        const float* p0 = x + (((unsigned long long)b*128 + 2*cp)*64 + gr)*64 + lane;
        unsigned lo = f2bf(p0[0]);
        unsigned hi = f2bf(p0[64*64]);
        ls32[cp*66 + lane] = lo | (hi << 16);
    }
    __syncthreads();
    for (int d = tid; d < 1056; d += 256) {
        int cic  = d / 264;
        int r    = d - cic*264;
        int lcol = r >> 2;
        int cg   = r & 3;
        int4 v;
        if (lcol == 0 || lcol == 65) {
            v = make_int4(0,0,0,0);
        } else {
            int col  = lcol - 1;
            int base = (cic*16 + cg*4)*66 + col;
            v.x = ls32[base];
            v.y = ls32[base + 66];
            v.z = ls32[base + 2*66];
            v.w = ls32[base + 3*66];
        }
        int p = (cg + (lcol >> 1)) & 3;             // bank-conflict-free swizzle
        int4* dst = (int4*)(xbfT + ((unsigned long long)((b*4 + cic)*66 + rr))*(66*32));
        dst[lcol*4 + p] = v;
    }
}

// ---------------- kernel D: implicit-GEMM conv, bf16 MFMA ----------------
// grid 512 (32 b x 16 row-tiles), 256 threads (4 waves), each wave = 1 output row
__global__ __launch_bounds__(256, 2) void conv_kernel(
    const unsigned short* __restrict__ xbfT,
    const unsigned short* __restrict__ dynw,
    const float* __restrict__ dynb,
    float* __restrict__ out)
{
    __shared__ __align__(16) unsigned short xs[6*66*32];      // 25344 B
    __shared__ __align__(16) unsigned short wsm[2][128*32];   // 16384 B

    const int tid  = threadIdx.x;
    const int wave = tid >> 6;
    const int lane = tid & 63;
    const int l15  = lane & 15;
    const int g    = lane >> 4;

    // bijective XCD swizzle (512 blocks, 8 XCDs -> 64 contiguous per XCD)
    int bidx = ((blockIdx.x & 7) << 6) | (blockIdx.x >> 3);
    const int b  = bidx >> 4;
    const int r0 = (bidx & 15) << 2;

    f32x4 acc[8][4];
#pragma unroll
    for (int mi = 0; mi < 8; ++mi)
#pragma unroll
        for (int ni = 0; ni < 4; ++ni) acc[mi][ni] = (f32x4){0.f,0.f,0.f,0.f};

    const unsigned short* xsrcb = xbfT + (unsigned long long)b*(4ull*66*66*32);
    const unsigned short* wsrcb = dynw + (unsigned long long)b*(4ull*9*128*32);

    int a_off[8];
#pragma unroll
    for (int mi = 0; mi < 8; ++mi) {
        int co = 16*mi + l15;
        a_off[mi] = co*64 + (((g + (co >> 1)) & 3) << 4);
    }

    // prologue: stage xs(cic 0) + wsm[0](tap 0), all linear global_load_lds
    {
        const unsigned short* src = xsrcb + (unsigned)r0*(66*32);
        for (int c = tid; c < 1584; c += 256) gl2lds16(src + c*8, xs + c*8);
        for (int c = tid; c < 512; c += 256)  gl2lds16(wsrcb + c*8, wsm[0] + c*8);
    }
    __syncthreads();

    int cur = 0;
    for (int cic = 0; cic < 4; ++cic) {
        for (int tap = 0; tap < 9; ++tap) {
            {   // prefetch next tap's weights into the other buffer (overlaps MFMA)
                int nidx = cic*9 + tap + 1;
                if (nidx < 36) {
                    const unsigned short* wsrc = wsrcb + (unsigned)nidx*4096;
                    unsigned short* wd = wsm[cur ^ 1];
                    for (int c = tid; c < 512; c += 256) gl2lds16(wsrc + c*8, wd + c*8);
                }
            }
            const int ky = tap / 3, kx = tap - ky*3;
            bf16x8 bfrag[4];
#pragma unroll
            for (int ni = 0; ni < 4; ++ni) {
                int lcol = 16*ni + l15 + kx;
                int boff = ((wave + ky)*66 + lcol)*64 + (((g + (lcol >> 1)) & 3) << 4);
                bfrag[ni] = *(const bf16x8*)((const char*)xs + boff);
            }
            const unsigned short* wb = wsm[cur];
#pragma unroll
            for (int mi = 0; mi < 8; ++mi) {
                bf16x8 afrag = *(const bf16x8*)((const char*)wb + a_off[mi]);
#pragma unroll
                for (int ni = 0; ni < 4; ++ni)
                    acc[mi][ni] = __builtin_amdgcn_mfma_f32_16x16x32_bf16(
                                      afrag, bfrag[ni], acc[mi][ni], 0, 0, 0);
            }
            __syncthreads();   // single barrier per K-step (drain covered by MFMA)
            cur ^= 1;
        }
        if (cic < 3) {   // re-stage xs for next ci chunk
            const unsigned short* src = xsrcb + (unsigned)(cic+1)*(66*66*32)
                                      + (unsigned)r0*(66*32);
            for (int c = tid; c < 1584; c += 256) gl2lds16(src + c*8, xs + c*8);
            __syncthreads();
        }
    }

    // epilogue: D row = co = 16*mi + g*4 + r ; col = 16*ni + l15 ; y = r0 + wave
    const int y = r0 + wave;
#pragma unroll
    for (int mi = 0; mi < 8; ++mi) {
#pragma unroll
        for (int r = 0; r < 4; ++r) {
            int co = 16*mi + g*4 + r;
            float bias = dynb[b*128 + co];
            float* op = out + (((unsigned long long)(b*128 + co))*64 + y)*64;
#pragma unroll
            for (int ni = 0; ni < 4; ++ni)
                op[16*ni + l15] = acc[mi][ni][r] + bias;
        }
    }
}

extern "C" void kernel_launch(void* const* d_in, const int* in_sizes, int n_in,
                              void* d_out, int out_size, void* d_ws, size_t ws_size,
                              hipStream_t stream)
{
    const float* x     = (const float*)d_in[0];
    const float* stats = (const float*)d_in[1];
    const float* W1    = (const float*)d_in[2];
    const float* b1    = (const float*)d_in[3];
    const float* W2    = (const float*)d_in[4];
    const float* b2    = (const float*)d_in[5];
    const float* wexp  = (const float*)d_in[6];
    const float* bexp  = (const float*)d_in[7];
    float* out = (float*)d_out;

    char* ws = (char*)d_ws;
    float* routing        = (float*)ws;                              // 512 B
    float* dynb           = (float*)(ws + 512);                      // 16 KB
    unsigned short* dynw  = (unsigned short*)(ws + 32768);           // 9,437,184 B
    unsigned short* xbfT  = (unsigned short*)(ws + 32768 + 9437184); // 35,684,352 B

    router_kernel<<<1, 64, 0, stream>>>(stats, W1, b1, W2, b2, routing);
    dynw_kernel<<<dim3(128, 4), 256, 0, stream>>>(wexp, bexp, routing, dynw, dynb);
    xcvt_kernel<<<32*66, 256, 0, stream>>>(x, xbfT);
    conv_kernel<<<512, 256, 0, stream>>>(xbfT, dynw, dynb, out);
}